// Round 10
// baseline (5423.291 us; speedup 1.0000x reference)
//
#include <hip/hip_runtime.h>
#include <hip/hip_bf16.h>

#define SEQ   512
#define HID   1024
#define NBLK  256
#define NTHR  256
#define PADK  2056   // LDS weight row stride (shorts); 4112 B, 16B-aligned
#define GPS   32     // gparts row stride (dwords): reads are addr=4*tid, conflict-free

typedef __attribute__((ext_vector_type(8))) short bf16x8;
typedef __attribute__((ext_vector_type(4))) float f32x4;
typedef __attribute__((ext_vector_type(2))) float f32x2;

struct Params {
  const float* x;        // [64][512][1024] f32
  const float* Wi[4];    // [1024][1024] f32, gates i,f,g,o
  const float* Wh[4];
  const float* bi[4];
  const float* bh[4];
  float* out;            // f32 [h_T | c_T]; fallback tier also uses halves as h ping-pong
  const short* xbf;      // mode 1: x pre-converted to bf16
  short* hb0;            // mode 1: bf16 h ping-pong (sc1/IF-coherent)
  short* hb1;
  unsigned* arrive;      // PADDED flags arrive[bid*32] (128 B per producer line)
  unsigned* gen;         // generation flag (fallback tier only)
};

__device__ __forceinline__ float sig_(float v)  { return 1.0f / (1.0f + __expf(-v)); }
__device__ __forceinline__ float tanh_(float v) { return 1.0f - 2.0f / (__expf(2.0f * v) + 1.0f); }

__device__ __forceinline__ short f2b(float f) {   // f32 -> bf16 RNE
  unsigned u = __builtin_bit_cast(unsigned, f);
  u += 0x7FFFu + ((u >> 16) & 1u);
  return (short)(u >> 16);
}
__device__ __forceinline__ bf16x8 cvt8(const float* p) {
  f32x4 a = *(const f32x4*)p;
  f32x4 b = *(const f32x4*)(p + 4);
  bf16x8 r;
  r[0] = f2b(a[0]); r[1] = f2b(a[1]); r[2] = f2b(a[2]); r[3] = f2b(a[3]);
  r[4] = f2b(b[0]); r[5] = f2b(b[1]); r[6] = f2b(b[2]); r[7] = f2b(b[3]);
  return r;
}

// 16B load bypassing L1/L2 (device-coherent, served by Infinity Cache).
// Caller MUST batch these then execute wait_vm0() + launder before use.
__device__ __forceinline__ bf16x8 ld16_sc1(const short* p) {
  bf16x8 r;
  asm volatile("global_load_dwordx4 %0, %1, off sc1" : "=v"(r) : "v"(p));
  return r;
}
__device__ __forceinline__ void wait_vm0() {
  asm volatile("s_waitcnt vmcnt(0)" ::: "memory");
}

__global__ __launch_bounds__(256) void init_ws(unsigned* bar, unsigned* hzero, int hn) {
  int i = blockIdx.x * blockDim.x + threadIdx.x;
  if (i < 8448) bar[i] = 0u;              // flag slots (8192) + gen + pad
  if (i < hn) hzero[i] = 0u;              // zero h(t=0) buffer
}

__global__ __launch_bounds__(256) void cvt_x(const float* __restrict__ x,
                                             short* __restrict__ xb) {
  size_t i = ((size_t)blockIdx.x * 256 + threadIdx.x) * 8;
  *(bf16x8*)(xb + i) = cvt8(x + i);
}

// ---- fallback-tier barrier (fence-based; correctness only) ----
__device__ __forceinline__ void gbar_fence(unsigned* arrive, unsigned* gen,
                                           int tid, int bid, unsigned tgt) {
  __syncthreads();
  if (bid == 0) {
    if (tid != 0) {
      int polls = 0;
      while (__hip_atomic_load(&arrive[tid * 32], __ATOMIC_RELAXED,
                               __HIP_MEMORY_SCOPE_AGENT) < tgt) {
        __builtin_amdgcn_s_sleep(1);
        if (++polls > (1 << 22)) break;
      }
    }
    __syncthreads();
    if (tid == 0) {
      __threadfence();
      __hip_atomic_store(gen, tgt, __ATOMIC_RELEASE, __HIP_MEMORY_SCOPE_AGENT);
    }
    __syncthreads();
  } else {
    if (tid == 0) {
      __threadfence();
      __hip_atomic_store(&arrive[bid * 32], tgt, __ATOMIC_RELEASE,
                         __HIP_MEMORY_SCOPE_AGENT);
      int polls = 0;
      while (__hip_atomic_load(gen, __ATOMIC_RELAXED,
                               __HIP_MEMORY_SCOPE_AGENT) < tgt) {
        __builtin_amdgcn_s_sleep(1);
        if (++polls > (1 << 22)) break;
      }
      __threadfence();
    }
    __syncthreads();
  }
}

// MODE: 1 = xbf + sc1 ping-pong h + padded flags + busy-poll + WEIGHTS-IN-VGPRS
//       + conflict-free cell update; 0 = f32 fallback (same compute structure)
// LDS: bls[32][PADK] bf16 (row = interleaved gate-col 4*jl+g), 131584 B
//      gparts[4][32][GPS] f32 (16384), cst[256] f32 (1024), bias_s[32] f32 (128)
//      total = 149120 B
template <int MODE>
__global__ __launch_bounds__(NTHR, 1) void lstm_persistent(Params p) {
  extern __shared__ char smem[];
  short* bls    = (short*)smem;
  float* gparts = (float*)(smem + 131584);
  float* cst    = (float*)(smem + 131584 + 16384);
  float* bias_s = (float*)(smem + 131584 + 16384 + 1024);

  const int tid = threadIdx.x;
  const int bid = blockIdx.x;
  const int cg  = bid & 127;       // gate-col group: cols [32cg, 32cg+32)
  const int mh  = bid >> 7;        // batch half
  const int r0  = mh * 32;
  const int j0  = cg * 8;          // hidden cols [j0, j0+8)

  // ---- one-time: stage bf16 weight slab, interleaved col = 4*jl + g ----
  {
    const int g    = tid & 3;
    const int krow = tid >> 2;     // 0..63
    const float* wi = p.Wi[g];
    const float* wh = p.Wh[g];
    for (int kb = 0; kb < 2048; kb += 64) {
      int k = kb + krow;
      const float* src = (k < HID) ? (wi + (size_t)k * HID + j0)
                                   : (wh + (size_t)(k - HID) * HID + j0);
      f32x4 va = *(const f32x4*)src;
      f32x4 vb = *(const f32x4*)(src + 4);
      #pragma unroll
      for (int jj = 0; jj < 4; ++jj) {
        bls[(4 * jj + g) * PADK + k]       = f2b(va[jj]);
        bls[(4 * (jj + 4) + g) * PADK + k] = f2b(vb[jj]);
      }
    }
  }
  if (tid < 32) {
    int g = tid & 3, j = j0 + (tid >> 2);
    bias_s[tid] = p.bi[g][j] + p.bh[g][j];
  }
  cst[tid] = 0.0f;
  __syncthreads();

  const int lane = tid & 63;
  const int ksl  = tid >> 6;       // K-slice 0..3; 0,1 = x-part, 2,3 = h-part
  const int m16  = lane & 15;
  const int quad = lane >> 4;
  const size_t rm0 = (size_t)(r0 + m16);
  const size_t rm1 = (size_t)(r0 + 16 + m16);
  const short* bB0 = bls + (size_t)m16 * PADK + ksl * 512 + quad * 8;        // nt=0
  const short* bB1 = bls + (size_t)(16 + m16) * PADK + ksl * 512 + quad * 8; // nt=1

  // ---- WEIGHTS -> REGISTERS (one-time): 32 x bf16x8 = 128 VGPRs per wave.
  // Eliminates 128 ds_read_b128 per step per CU (the largest per-step LDS
  // cost, re-paid 512x before). 1 block/CU (LDS-bound), so VGPR headroom
  // is 512/wave — no occupancy loss.
  bf16x8 W0[16], W1[16];
  #pragma unroll
  for (int ki = 0; ki < 16; ++ki) {
    W0[ki] = *(const bf16x8*)(bB0 + ki * 32);
    W1[ki] = *(const bf16x8*)(bB1 + ki * 32);
  }

  // Each h-wave depends on exactly the 64 producer blocks of its K-half:
  // ksl=2 reads h cols [0,512) <- blocks mh*128+[0,64); ksl=3 <- +64.
  // Lane L polls producer (mh*128 + (ksl-2)*64 + L); divergent loop = wave AND.
  // PADDED flag lines (128 B/producer): R5/R7 showed concentrating flag
  // traffic on few lines serializes at the IF bank — keep the spread layout.
  const unsigned* myflag =
      p.arrive + (size_t)(mh * 128 + (ksl - 2) * 64 + lane) * 32;

  float cfin = 0.0f;
  const int rl = tid >> 3;         // cell-update row (0..31)
  const int jl = tid & 7;          // cell-update hidden col (0..7)

  for (int t = 0; t < SEQ; ++t) {
    f32x4 acc00 = {0,0,0,0}, acc01 = {0,0,0,0};
    f32x4 acc10 = {0,0,0,0}, acc11 = {0,0,0,0};

    if constexpr (MODE == 1) {
      if (ksl < 2) {
        // x-part: bf16 pre-converted, runs ahead, never waits on flags
        const short* xb = p.xbf + ksl * 512 + quad * 8 + (size_t)t * HID;
        const short* pa0 = xb + rm0 * (SEQ * HID);
        const short* pa1 = xb + rm1 * (SEQ * HID);
        #pragma unroll 4
        for (int ki = 0; ki < 16; ++ki) {
          bf16x8 a0 = *(const bf16x8*)(pa0 + ki * 32);
          bf16x8 a1 = *(const bf16x8*)(pa1 + ki * 32);
          acc00 = __builtin_amdgcn_mfma_f32_16x16x32_bf16(a0, W0[ki], acc00, 0, 0, 0);
          acc01 = __builtin_amdgcn_mfma_f32_16x16x32_bf16(a0, W1[ki], acc01, 0, 0, 0);
          acc10 = __builtin_amdgcn_mfma_f32_16x16x32_bf16(a1, W0[ki], acc10, 0, 0, 0);
          acc11 = __builtin_amdgcn_mfma_f32_16x16x32_bf16(a1, W1[ki], acc11, 0, 0, 0);
        }
      } else if (t > 0) {          // t==0: h=0, h-MFMA contributes 0 — skip
        // one-hop flag wait, anti-throttle pacing (R8 mechanism, kept)
        if (__hip_atomic_load(myflag, __ATOMIC_RELAXED,
                              __HIP_MEMORY_SCOPE_AGENT) < (unsigned)t) {
          float z = (float)(lane + 1);
          int polls = 0;
          do {
            #pragma unroll 1
            for (int d = 0; d < 64; ++d)      // dependent v_fma delay ~256 cy
              z = __builtin_fmaf(z, 1.0000001f, 1.1920929e-7f);
            asm volatile("" : "+v"(z));
            if (++polls > (1 << 20)) break;
          } while (__hip_atomic_load(myflag, __ATOMIC_RELAXED,
                                     __HIP_MEMORY_SCOPE_AGENT) < (unsigned)t);
        }
        // batched IF-coherent sc1 loads, single vmcnt wait (round-3 mechanism)
        const short* hr = ((t & 1) ? p.hb1 : p.hb0) + (ksl - 2) * 512 + quad * 8;
        const short* pa0 = hr + rm0 * HID;
        const short* pa1 = hr + rm1 * HID;
        bf16x8 A0[16], A1[16];
        #pragma unroll
        for (int ki = 0; ki < 16; ++ki) {
          A0[ki] = ld16_sc1(pa0 + ki * 32);
          A1[ki] = ld16_sc1(pa1 + ki * 32);
        }
        wait_vm0();
        #pragma unroll
        for (int ki = 0; ki < 16; ++ki) {   // launder: pin MFMAs after the wait
          asm volatile("" : "+v"(A0[ki]));
          asm volatile("" : "+v"(A1[ki]));
        }
        #pragma unroll
        for (int ki = 0; ki < 16; ++ki) {
          acc00 = __builtin_amdgcn_mfma_f32_16x16x32_bf16(A0[ki], W0[ki], acc00, 0, 0, 0);
          acc01 = __builtin_amdgcn_mfma_f32_16x16x32_bf16(A0[ki], W1[ki], acc01, 0, 0, 0);
          acc10 = __builtin_amdgcn_mfma_f32_16x16x32_bf16(A1[ki], W0[ki], acc10, 0, 0, 0);
          acc11 = __builtin_amdgcn_mfma_f32_16x16x32_bf16(A1[ki], W1[ki], acc11, 0, 0, 0);
        }
      }
    } else {
      const float *fa0, *fa1;
      if (ksl < 2) {
        const float* xb = p.x + ksl * 512 + quad * 8 + (size_t)t * HID;
        fa0 = xb + rm0 * (SEQ * HID);
        fa1 = xb + rm1 * (SEQ * HID);
      } else {
        const float* hr = (p.out + ((t & 1) ? 65536 : 0)) + (ksl - 2) * 512 + quad * 8;
        fa0 = hr + rm0 * HID;
        fa1 = hr + rm1 * HID;
      }
      #pragma unroll 2
      for (int ki = 0; ki < 16; ++ki) {
        bf16x8 a0 = cvt8(fa0 + ki * 32);
        bf16x8 a1 = cvt8(fa1 + ki * 32);
        acc00 = __builtin_amdgcn_mfma_f32_16x16x32_bf16(a0, W0[ki], acc00, 0, 0, 0);
        acc01 = __builtin_amdgcn_mfma_f32_16x16x32_bf16(a0, W1[ki], acc01, 0, 0, 0);
        acc10 = __builtin_amdgcn_mfma_f32_16x16x32_bf16(a1, W0[ki], acc10, 0, 0, 0);
        acc11 = __builtin_amdgcn_mfma_f32_16x16x32_bf16(a1, W1[ki], acc11, 0, 0, 0);
      }
    }

    // C layout: col = lane&15, row = quad*4 + reg (HW-verified)
    {
      float* gp = gparts + ksl * (32 * GPS);
      #pragma unroll
      for (int r = 0; r < 4; ++r) {
        gp[(quad * 4 + r) * GPS + m16]           = acc00[r];
        gp[(quad * 4 + r) * GPS + 16 + m16]      = acc01[r];
        gp[(16 + quad * 4 + r) * GPS + m16]      = acc10[r];
        gp[(16 + quad * 4 + r) * GPS + 16 + m16] = acc11[r];
      }
    }
    __syncthreads();   // S2: gparts(t) complete before cell reads

    // ---- cell update: 256 threads, ONE hidden col each (rl, jl).
    // gparts col c = 4*jl + g (gate interleave) => f32x4 at col 4*jl is
    // exactly (i,f,g,o). Read addr dword = s*1024 + 4*tid: contiguous per
    // slice => conflict-free (was 8-way with the old pair-gather).
    {
      f32x4 gv = {0,0,0,0};
      #pragma unroll
      for (int s = 0; s < 4; ++s)
        gv += *(const f32x4*)(gparts + s * (32 * GPS) + rl * GPS + jl * 4);
      f32x4 bv = *(const f32x4*)(bias_s + jl * 4);

      float iv = sig_(gv[0] + bv[0]);
      float fv = sig_(gv[1] + bv[1]);
      float gg = tanh_(gv[2] + bv[2]);
      float ov = sig_(gv[3] + bv[3]);

      float cnew = fv * cst[tid] + iv * gg;
      cst[tid] = cnew;
      float hv = ov * tanh_(cnew);

      size_t off = (size_t)(r0 + rl) * HID + j0 + jl;
      if constexpr (MODE == 1) {
        unsigned hu = (unsigned)(unsigned short)f2b(hv);
        unsigned hn = __shfl_down(hu, 1);   // neighbor col's bf16 (jl+1)
        if (t < SEQ - 1) {
          short* hw = (t & 1) ? p.hb0 : p.hb1;
          if ((jl & 1) == 0)
            // IF-coherent h store (sc1, compiler-tracked for S3 drain)
            __hip_atomic_store((unsigned*)(hw + off), hu | (hn << 16),
                               __ATOMIC_RELAXED, __HIP_MEMORY_SCOPE_AGENT);
        } else {
          p.out[off] = hv;
          p.out[65536 + off] = cnew;
        }
      } else {
        float* hw = p.out + ((t & 1) ? 0 : 65536);
        hw[off] = hv;
        if (t == SEQ - 1) cfin = cnew;
      }
    }

    if constexpr (MODE == 1) {
      // S3: every wave drains its vmcnt (h sc1 stores acked at IF) before the
      // barrier completes; tid0's flag store below is therefore ordered after
      // ALL of this block's h stores at the coherence point.
      __syncthreads();
      if (t < SEQ - 1 && tid == 0)
        __hip_atomic_store(&p.arrive[(size_t)bid * 32], (unsigned)(t + 1),
                           __ATOMIC_RELAXED, __HIP_MEMORY_SCOPE_AGENT);
    } else {
      if (t < SEQ - 1)
        gbar_fence(p.arrive, p.gen, tid, bid, (unsigned)(t + 1));
    }
  }

  if constexpr (MODE == 0) {
    size_t off = (size_t)(r0 + rl) * HID + j0 + jl;
    p.out[65536 + off] = cfin;
  }
}

extern "C" void kernel_launch(void* const* d_in, const int* in_sizes, int n_in,
                              void* d_out, int out_size, void* d_ws, size_t ws_size,
                              hipStream_t stream) {
  Params prm;
  prm.x = (const float*)d_in[0];
  for (int g = 0; g < 4; ++g) {
    prm.Wi[g] = (const float*)d_in[1 + g];
    prm.Wh[g] = (const float*)d_in[5 + g];
    prm.bi[g] = (const float*)d_in[9 + 2 * g];
    prm.bh[g] = (const float*)d_in[10 + 2 * g];
  }
  prm.out    = (float*)d_out;
  prm.arrive = (unsigned*)d_ws;
  prm.gen    = prm.arrive + 8192;          // own 128 B line after slot region
  prm.xbf = nullptr; prm.hb0 = nullptr; prm.hb1 = nullptr;

  const size_t XBF   = 67108864;                      // 64 MiB
  const size_t need1 = 65536 + XBF + 2 * 131072;      // 67,436,544 (known avail.)
  const int mode = (ws_size >= need1) ? 1 : 0;

  if (mode == 1) {
    prm.xbf = (const short*)((char*)d_ws + 65536);
    prm.hb0 = (short*)((char*)d_ws + 65536 + XBF);
    prm.hb1 = prm.hb0 + 65536;
  }

  const int smem_bytes = 131584 + 16384 + 1024 + 128;   // 149120
  hipFuncSetAttribute((const void*)lstm_persistent<1>,
                      hipFuncAttributeMaxDynamicSharedMemorySize, smem_bytes);
  hipFuncSetAttribute((const void*)lstm_persistent<0>,
                      hipFuncAttributeMaxDynamicSharedMemorySize, smem_bytes);

  if (mode == 1) {
    init_ws<<<256, 256, 0, stream>>>((unsigned*)d_ws, (unsigned*)prm.hb0, 32768);
    cvt_x<<<16384, 256, 0, stream>>>(prm.x, (short*)prm.xbf);
    lstm_persistent<1><<<NBLK, NTHR, smem_bytes, stream>>>(prm);
  } else {
    init_ws<<<256, 256, 0, stream>>>((unsigned*)d_ws, (unsigned*)d_out, 65536);
    lstm_persistent<0><<<NBLK, NTHR, smem_bytes, stream>>>(prm);
  }
}

// Round 11
// 3360.809 us; speedup vs baseline: 1.6137x; 1.6137x over previous
//
#include <hip/hip_runtime.h>
#include <hip/hip_bf16.h>

#define SEQ   512
#define HID   1024
#define NBLK  256
#define NTHR  256
#define PADK  2056   // LDS weight row stride (shorts); 4112 B, 16B-aligned
#define GPS   32     // gparts row stride (dwords): reads are addr=4*tid, conflict-free

typedef __attribute__((ext_vector_type(8))) short bf16x8;
typedef __attribute__((ext_vector_type(4))) float f32x4;
typedef __attribute__((ext_vector_type(2))) float f32x2;

struct Params {
  const float* x;        // [64][512][1024] f32
  const float* Wi[4];    // [1024][1024] f32, gates i,f,g,o
  const float* Wh[4];
  const float* bi[4];
  const float* bh[4];
  float* out;            // f32 [h_T | c_T]; fallback tier also uses halves as h ping-pong
  const short* xbf;      // mode 1: x pre-converted to bf16
  short* hb0;            // mode 1: bf16 h ping-pong (sc1/IF-coherent)
  short* hb1;
  unsigned* arrive;      // PADDED flags arrive[bid*32] (128 B per producer line)
  unsigned* gen;         // generation flag (fallback tier only)
};

__device__ __forceinline__ float sig_(float v)  { return 1.0f / (1.0f + __expf(-v)); }
__device__ __forceinline__ float tanh_(float v) { return 1.0f - 2.0f / (__expf(2.0f * v) + 1.0f); }

__device__ __forceinline__ short f2b(float f) {   // f32 -> bf16 RNE
  unsigned u = __builtin_bit_cast(unsigned, f);
  u += 0x7FFFu + ((u >> 16) & 1u);
  return (short)(u >> 16);
}
__device__ __forceinline__ bf16x8 cvt8(const float* p) {
  f32x4 a = *(const f32x4*)p;
  f32x4 b = *(const f32x4*)(p + 4);
  bf16x8 r;
  r[0] = f2b(a[0]); r[1] = f2b(a[1]); r[2] = f2b(a[2]); r[3] = f2b(a[3]);
  r[4] = f2b(b[0]); r[5] = f2b(b[1]); r[6] = f2b(b[2]); r[7] = f2b(b[3]);
  return r;
}

// 16B load bypassing L1/L2 (device-coherent, served by Infinity Cache).
// Caller MUST batch these then execute wait_vm0() + launder before use.
__device__ __forceinline__ bf16x8 ld16_sc1(const short* p) {
  bf16x8 r;
  asm volatile("global_load_dwordx4 %0, %1, off sc1" : "=v"(r) : "v"(p));
  return r;
}
__device__ __forceinline__ void wait_vm0() {
  asm volatile("s_waitcnt vmcnt(0)" ::: "memory");
}

__global__ __launch_bounds__(256) void init_ws(unsigned* bar, unsigned* hzero, int hn) {
  int i = blockIdx.x * blockDim.x + threadIdx.x;
  if (i < 8448) bar[i] = 0u;              // flag slots (8192) + gen + pad
  if (i < hn) hzero[i] = 0u;              // zero h(t=0) buffer
}

__global__ __launch_bounds__(256) void cvt_x(const float* __restrict__ x,
                                             short* __restrict__ xb) {
  size_t i = ((size_t)blockIdx.x * 256 + threadIdx.x) * 8;
  *(bf16x8*)(xb + i) = cvt8(x + i);
}

// ---- fallback-tier barrier (fence-based; correctness only) ----
__device__ __forceinline__ void gbar_fence(unsigned* arrive, unsigned* gen,
                                           int tid, int bid, unsigned tgt) {
  __syncthreads();
  if (bid == 0) {
    if (tid != 0) {
      int polls = 0;
      while (__hip_atomic_load(&arrive[tid * 32], __ATOMIC_RELAXED,
                               __HIP_MEMORY_SCOPE_AGENT) < tgt) {
        __builtin_amdgcn_s_sleep(1);
        if (++polls > (1 << 22)) break;
      }
    }
    __syncthreads();
    if (tid == 0) {
      __threadfence();
      __hip_atomic_store(gen, tgt, __ATOMIC_RELEASE, __HIP_MEMORY_SCOPE_AGENT);
    }
    __syncthreads();
  } else {
    if (tid == 0) {
      __threadfence();
      __hip_atomic_store(&arrive[bid * 32], tgt, __ATOMIC_RELEASE,
                         __HIP_MEMORY_SCOPE_AGENT);
      int polls = 0;
      while (__hip_atomic_load(gen, __ATOMIC_RELAXED,
                               __HIP_MEMORY_SCOPE_AGENT) < tgt) {
        __builtin_amdgcn_s_sleep(1);
        if (++polls > (1 << 22)) break;
      }
      __threadfence();
    }
    __syncthreads();
  }
}

// MODE: 1 = xbf + sc1 ping-pong h + padded flags + busy-poll + WEIGHTS-IN-VGPRS
//       (ALL loops touching W fully unrolled — partial unroll leaves a runtime
//        index and demotes the W arrays to scratch: R10's 5.9 GB FETCH, VGPR=100)
//       + conflict-free cell update; 0 = f32 fallback (same compute structure)
// LDS: bls[32][PADK] bf16 (row = interleaved gate-col 4*jl+g), 131584 B
//      gparts[4][32][GPS] f32 (16384), cst[256] f32 (1024), bias_s[32] f32 (128)
//      total = 149120 B
template <int MODE>
__global__ __launch_bounds__(NTHR, 1) void lstm_persistent(Params p) {
  extern __shared__ char smem[];
  short* bls    = (short*)smem;
  float* gparts = (float*)(smem + 131584);
  float* cst    = (float*)(smem + 131584 + 16384);
  float* bias_s = (float*)(smem + 131584 + 16384 + 1024);

  const int tid = threadIdx.x;
  const int bid = blockIdx.x;
  const int cg  = bid & 127;       // gate-col group: cols [32cg, 32cg+32)
  const int mh  = bid >> 7;        // batch half
  const int r0  = mh * 32;
  const int j0  = cg * 8;          // hidden cols [j0, j0+8)

  // ---- one-time: stage bf16 weight slab, interleaved col = 4*jl + g ----
  {
    const int g    = tid & 3;
    const int krow = tid >> 2;     // 0..63
    const float* wi = p.Wi[g];
    const float* wh = p.Wh[g];
    for (int kb = 0; kb < 2048; kb += 64) {
      int k = kb + krow;
      const float* src = (k < HID) ? (wi + (size_t)k * HID + j0)
                                   : (wh + (size_t)(k - HID) * HID + j0);
      f32x4 va = *(const f32x4*)src;
      f32x4 vb = *(const f32x4*)(src + 4);
      #pragma unroll
      for (int jj = 0; jj < 4; ++jj) {
        bls[(4 * jj + g) * PADK + k]       = f2b(va[jj]);
        bls[(4 * (jj + 4) + g) * PADK + k] = f2b(vb[jj]);
      }
    }
  }
  if (tid < 32) {
    int g = tid & 3, j = j0 + (tid >> 2);
    bias_s[tid] = p.bi[g][j] + p.bh[g][j];
  }
  cst[tid] = 0.0f;
  __syncthreads();

  const int lane = tid & 63;
  const int ksl  = tid >> 6;       // K-slice 0..3; 0,1 = x-part, 2,3 = h-part
  const int m16  = lane & 15;
  const int quad = lane >> 4;
  const size_t rm0 = (size_t)(r0 + m16);
  const size_t rm1 = (size_t)(r0 + 16 + m16);
  const short* bB0 = bls + (size_t)m16 * PADK + ksl * 512 + quad * 8;        // nt=0
  const short* bB1 = bls + (size_t)(16 + m16) * PADK + ksl * 512 + quad * 8; // nt=1

  // ---- WEIGHTS -> REGISTERS (one-time): 32 x bf16x8 = 128 VGPRs per wave.
  // Every subsequent access uses a compile-time index (full unrolls below),
  // so the allocator keeps these in VGPRs (rule: runtime-indexed ext_vector
  // arrays are demoted to scratch — exactly R10's failure).
  bf16x8 W0[16], W1[16];
  #pragma unroll
  for (int ki = 0; ki < 16; ++ki) {
    W0[ki] = *(const bf16x8*)(bB0 + ki * 32);
    W1[ki] = *(const bf16x8*)(bB1 + ki * 32);
  }

  // Each h-wave depends on exactly the 64 producer blocks of its K-half:
  // ksl=2 reads h cols [0,512) <- blocks mh*128+[0,64); ksl=3 <- +64.
  // Lane L polls producer (mh*128 + (ksl-2)*64 + L); divergent loop = wave AND.
  // PADDED flag lines (128 B/producer): R5/R7 showed concentrating flag
  // traffic on few lines serializes at the IF bank — keep the spread layout.
  const unsigned* myflag =
      p.arrive + (size_t)(mh * 128 + (ksl - 2) * 64 + lane) * 32;

  float cfin = 0.0f;
  const int rl = tid >> 3;         // cell-update row (0..31)
  const int jl = tid & 7;          // cell-update hidden col (0..7)

  for (int t = 0; t < SEQ; ++t) {
    f32x4 acc00 = {0,0,0,0}, acc01 = {0,0,0,0};
    f32x4 acc10 = {0,0,0,0}, acc11 = {0,0,0,0};

    if constexpr (MODE == 1) {
      if (ksl < 2) {
        // x-part: bf16 pre-converted, runs ahead, never waits on flags.
        // FULL unroll: W indices must stay compile-time (see above).
        const short* xb = p.xbf + ksl * 512 + quad * 8 + (size_t)t * HID;
        const short* pa0 = xb + rm0 * (SEQ * HID);
        const short* pa1 = xb + rm1 * (SEQ * HID);
        #pragma unroll
        for (int ki = 0; ki < 16; ++ki) {
          bf16x8 a0 = *(const bf16x8*)(pa0 + ki * 32);
          bf16x8 a1 = *(const bf16x8*)(pa1 + ki * 32);
          acc00 = __builtin_amdgcn_mfma_f32_16x16x32_bf16(a0, W0[ki], acc00, 0, 0, 0);
          acc01 = __builtin_amdgcn_mfma_f32_16x16x32_bf16(a0, W1[ki], acc01, 0, 0, 0);
          acc10 = __builtin_amdgcn_mfma_f32_16x16x32_bf16(a1, W0[ki], acc10, 0, 0, 0);
          acc11 = __builtin_amdgcn_mfma_f32_16x16x32_bf16(a1, W1[ki], acc11, 0, 0, 0);
        }
      } else if (t > 0) {          // t==0: h=0, h-MFMA contributes 0 — skip
        // one-hop flag wait, anti-throttle pacing (R8 mechanism, kept)
        if (__hip_atomic_load(myflag, __ATOMIC_RELAXED,
                              __HIP_MEMORY_SCOPE_AGENT) < (unsigned)t) {
          float z = (float)(lane + 1);
          int polls = 0;
          do {
            #pragma unroll 1
            for (int d = 0; d < 64; ++d)      // dependent v_fma delay ~256 cy
              z = __builtin_fmaf(z, 1.0000001f, 1.1920929e-7f);
            asm volatile("" : "+v"(z));
            if (++polls > (1 << 20)) break;
          } while (__hip_atomic_load(myflag, __ATOMIC_RELAXED,
                                     __HIP_MEMORY_SCOPE_AGENT) < (unsigned)t);
        }
        // batched IF-coherent sc1 loads, single vmcnt wait (round-3 mechanism)
        const short* hr = ((t & 1) ? p.hb1 : p.hb0) + (ksl - 2) * 512 + quad * 8;
        const short* pa0 = hr + rm0 * HID;
        const short* pa1 = hr + rm1 * HID;
        bf16x8 A0[16], A1[16];
        #pragma unroll
        for (int ki = 0; ki < 16; ++ki) {
          A0[ki] = ld16_sc1(pa0 + ki * 32);
          A1[ki] = ld16_sc1(pa1 + ki * 32);
        }
        wait_vm0();
        #pragma unroll
        for (int ki = 0; ki < 16; ++ki) {   // launder: pin MFMAs after the wait
          asm volatile("" : "+v"(A0[ki]));
          asm volatile("" : "+v"(A1[ki]));
        }
        #pragma unroll
        for (int ki = 0; ki < 16; ++ki) {
          acc00 = __builtin_amdgcn_mfma_f32_16x16x32_bf16(A0[ki], W0[ki], acc00, 0, 0, 0);
          acc01 = __builtin_amdgcn_mfma_f32_16x16x32_bf16(A0[ki], W1[ki], acc01, 0, 0, 0);
          acc10 = __builtin_amdgcn_mfma_f32_16x16x32_bf16(A1[ki], W0[ki], acc10, 0, 0, 0);
          acc11 = __builtin_amdgcn_mfma_f32_16x16x32_bf16(A1[ki], W1[ki], acc11, 0, 0, 0);
        }
      }
    } else {
      const float *fa0, *fa1;
      if (ksl < 2) {
        const float* xb = p.x + ksl * 512 + quad * 8 + (size_t)t * HID;
        fa0 = xb + rm0 * (SEQ * HID);
        fa1 = xb + rm1 * (SEQ * HID);
      } else {
        const float* hr = (p.out + ((t & 1) ? 65536 : 0)) + (ksl - 2) * 512 + quad * 8;
        fa0 = hr + rm0 * HID;
        fa1 = hr + rm1 * HID;
      }
      #pragma unroll
      for (int ki = 0; ki < 16; ++ki) {
        bf16x8 a0 = cvt8(fa0 + ki * 32);
        bf16x8 a1 = cvt8(fa1 + ki * 32);
        acc00 = __builtin_amdgcn_mfma_f32_16x16x32_bf16(a0, W0[ki], acc00, 0, 0, 0);
        acc01 = __builtin_amdgcn_mfma_f32_16x16x32_bf16(a0, W1[ki], acc01, 0, 0, 0);
        acc10 = __builtin_amdgcn_mfma_f32_16x16x32_bf16(a1, W0[ki], acc10, 0, 0, 0);
        acc11 = __builtin_amdgcn_mfma_f32_16x16x32_bf16(a1, W1[ki], acc11, 0, 0, 0);
      }
    }

    // C layout: col = lane&15, row = quad*4 + reg (HW-verified)
    {
      float* gp = gparts + ksl * (32 * GPS);
      #pragma unroll
      for (int r = 0; r < 4; ++r) {
        gp[(quad * 4 + r) * GPS + m16]           = acc00[r];
        gp[(quad * 4 + r) * GPS + 16 + m16]      = acc01[r];
        gp[(16 + quad * 4 + r) * GPS + m16]      = acc10[r];
        gp[(16 + quad * 4 + r) * GPS + 16 + m16] = acc11[r];
      }
    }
    __syncthreads();   // S2: gparts(t) complete before cell reads

    // ---- cell update: 256 threads, ONE hidden col each (rl, jl).
    // gparts col c = 4*jl + g (gate interleave) => f32x4 at col 4*jl is
    // exactly (i,f,g,o). Read addr dword = s*1024 + 4*tid: contiguous per
    // slice => conflict-free (R10 verified: conflicts 7.76e7 -> 1.69e7).
    {
      f32x4 gv = {0,0,0,0};
      #pragma unroll
      for (int s = 0; s < 4; ++s)
        gv += *(const f32x4*)(gparts + s * (32 * GPS) + rl * GPS + jl * 4);
      f32x4 bv = *(const f32x4*)(bias_s + jl * 4);

      float iv = sig_(gv[0] + bv[0]);
      float fv = sig_(gv[1] + bv[1]);
      float gg = tanh_(gv[2] + bv[2]);
      float ov = sig_(gv[3] + bv[3]);

      float cnew = fv * cst[tid] + iv * gg;
      cst[tid] = cnew;
      float hv = ov * tanh_(cnew);

      size_t off = (size_t)(r0 + rl) * HID + j0 + jl;
      if constexpr (MODE == 1) {
        unsigned hu = (unsigned)(unsigned short)f2b(hv);
        unsigned hn = __shfl_down(hu, 1);   // neighbor col's bf16 (jl+1)
        if (t < SEQ - 1) {
          short* hw = (t & 1) ? p.hb0 : p.hb1;
          if ((jl & 1) == 0)
            // IF-coherent h store (sc1, compiler-tracked for S3 drain)
            __hip_atomic_store((unsigned*)(hw + off), hu | (hn << 16),
                               __ATOMIC_RELAXED, __HIP_MEMORY_SCOPE_AGENT);
        } else {
          p.out[off] = hv;
          p.out[65536 + off] = cnew;
        }
      } else {
        float* hw = p.out + ((t & 1) ? 0 : 65536);
        hw[off] = hv;
        if (t == SEQ - 1) cfin = cnew;
      }
    }

    if constexpr (MODE == 1) {
      // S3: every wave drains its vmcnt (h sc1 stores acked at IF) before the
      // barrier completes; tid0's flag store below is therefore ordered after
      // ALL of this block's h stores at the coherence point.
      __syncthreads();
      if (t < SEQ - 1 && tid == 0)
        __hip_atomic_store(&p.arrive[(size_t)bid * 32], (unsigned)(t + 1),
                           __ATOMIC_RELAXED, __HIP_MEMORY_SCOPE_AGENT);
    } else {
      if (t < SEQ - 1)
        gbar_fence(p.arrive, p.gen, tid, bid, (unsigned)(t + 1));
    }
  }

  if constexpr (MODE == 0) {
    size_t off = (size_t)(r0 + rl) * HID + j0 + jl;
    p.out[65536 + off] = cfin;
  }
}

extern "C" void kernel_launch(void* const* d_in, const int* in_sizes, int n_in,
                              void* d_out, int out_size, void* d_ws, size_t ws_size,
                              hipStream_t stream) {
  Params prm;
  prm.x = (const float*)d_in[0];
  for (int g = 0; g < 4; ++g) {
    prm.Wi[g] = (const float*)d_in[1 + g];
    prm.Wh[g] = (const float*)d_in[5 + g];
    prm.bi[g] = (const float*)d_in[9 + 2 * g];
    prm.bh[g] = (const float*)d_in[10 + 2 * g];
  }
  prm.out    = (float*)d_out;
  prm.arrive = (unsigned*)d_ws;
  prm.gen    = prm.arrive + 8192;          // own 128 B line after slot region
  prm.xbf = nullptr; prm.hb0 = nullptr; prm.hb1 = nullptr;

  const size_t XBF   = 67108864;                      // 64 MiB
  const size_t need1 = 65536 + XBF + 2 * 131072;      // 67,436,544 (known avail.)
  const int mode = (ws_size >= need1) ? 1 : 0;

  if (mode == 1) {
    prm.xbf = (const short*)((char*)d_ws + 65536);
    prm.hb0 = (short*)((char*)d_ws + 65536 + XBF);
    prm.hb1 = prm.hb0 + 65536;
  }

  const int smem_bytes = 131584 + 16384 + 1024 + 128;   // 149120
  hipFuncSetAttribute((const void*)lstm_persistent<1>,
                      hipFuncAttributeMaxDynamicSharedMemorySize, smem_bytes);
  hipFuncSetAttribute((const void*)lstm_persistent<0>,
                      hipFuncAttributeMaxDynamicSharedMemorySize, smem_bytes);

  if (mode == 1) {
    init_ws<<<256, 256, 0, stream>>>((unsigned*)d_ws, (unsigned*)prm.hb0, 32768);
    cvt_x<<<16384, 256, 0, stream>>>(prm.x, (short*)prm.xbf);
    lstm_persistent<1><<<NBLK, NTHR, smem_bytes, stream>>>(prm);
  } else {
    init_ws<<<256, 256, 0, stream>>>((unsigned*)d_ws, (unsigned*)d_out, 65536);
    lstm_persistent<0><<<NBLK, NTHR, smem_bytes, stream>>>(prm);
  }
}